// Round 5
// baseline (73.014 us; speedup 1.0000x reference)
//
#include <hip/hip_runtime.h>

// db4 decomposition low-pass
static constexpr float H0 = -0.010597401784997278f;
static constexpr float H1 =  0.032883011666982945f;
static constexpr float H2 =  0.030841381835986965f;
static constexpr float H3 = -0.18703481171888114f;
static constexpr float H4 = -0.02798376941698385f;
static constexpr float H5 =  0.6308807679295904f;
static constexpr float H6 =  0.7148465705525415f;
static constexpr float H7 =  0.23037781330885523f;

// Correlation weights, per-level 0.5 folded in (exact pow2 scale).
static constexpr float W0[8] = { 0.5f*H0,  0.5f*H1,  0.5f*H2,  0.5f*H3,
                                 0.5f*H4,  0.5f*H5,  0.5f*H6,  0.5f*H7 };
static constexpr float W1[8] = {-0.5f*H7,  0.5f*H6, -0.5f*H5,  0.5f*H4,
                                -0.5f*H3,  0.5f*H2, -0.5f*H1,  0.5f*H0 };

constexpr int T     = 4096;
constexpr int BANDF = 1216;   // padded floats per band buffer (269 granules, pad 1 per 8)

// pad one 4-float granule per 8 granules: even bank coverage at granule-stride-1
static __device__ __forceinline__ int paddr_g(int g) { return (g << 2) + ((g >> 3) << 2); }
static __device__ __forceinline__ int paddr_f(int f) { return f + ((f >> 5) << 2); }

// Streaming-MAC inverse level: thread computes ONE output granule lg (4 floats).
// out[4lg + jp] = sum_k W0[k]*LO[4(lg-D) + jp + D*k] + W1[k]*HI[...]
// Window granules [lg-D, lg-D+NG); window float w = 4j+m contributes to
// (jp, k=(w-jp)/D) when (w-jp) % D == 0 and 0 <= (w-jp)/D < 8.
// All indices compile-time after unroll -> conditions fold, no register arrays.
template <int D, int NG>
static __device__ __forceinline__ void level_acc(const float* __restrict__ lo,
                                                 const float* __restrict__ hi,
                                                 int lg, float acc[4])
{
    acc[0] = acc[1] = acc[2] = acc[3] = 0.0f;
#pragma unroll
    for (int j = 0; j < NG; ++j) {
        const int a = paddr_g(lg - D + j);
        const float4 vl = *(const float4*)(lo + a);
        const float4 vh = *(const float4*)(hi + a);
        const float l[4] = {vl.x, vl.y, vl.z, vl.w};
        const float h[4] = {vh.x, vh.y, vh.z, vh.w};
#pragma unroll
        for (int m = 0; m < 4; ++m) {
            const int w = 4 * j + m;
#pragma unroll
            for (int jp = 0; jp < 4; ++jp) {
                const int d = w - jp;
                if (d >= 0 && (d % D) == 0 && (d / D) < 8) {
                    const int k = d / D;
                    acc[jp] = fmaf(W0[k], l[m], acc[jp]);
                    acc[jp] = fmaf(W1[k], h[m], acc[jp]);
                }
            }
        }
    }
}

__global__ __launch_bounds__(256, 6)
void iswt_kernel(const float* __restrict__ in, float* __restrict__ out)
{
    // 3 band buffers, 4.75 KB each = 14.25 KB/block -> 6 blocks/CU (VGPR-bound)
    __shared__ __align__(16) float X[BANDF], Y[BANDF], Z[BANDF];

    const int t   = threadIdx.x;
    const int bid = blockIdx.x;
    const int row = bid >> 2;
    const int t0  = (bid & 3) << 10;            // tile start position

    const float4* __restrict__ src = (const float4*)(in + (size_t)row * (T * 4));

    // ---- stage positions [t0-28, t0+1048) wrapped: X=cD_1 (.w), Y=cD_2 (.z);
    //      hold cA (.x) and cD_3 (.y) in registers for later ----
    float hA[5], hD3[5];
#pragma unroll
    for (int j = 0; j < 4; ++j) {
        const int fp = t + (j << 8);
        const int P  = (t0 - 28 + fp) & (T - 1);
        const float4 v = src[P];
        const int a = paddr_f(fp);
        X[a] = v.w;  Y[a] = v.z;
        hA[j] = v.x; hD3[j] = v.y;
    }
    if (t < 52) {
        const int fp = 1024 + t;
        const int P  = (t0 - 28 + fp) & (T - 1);
        const float4 v = src[P];
        const int a = paddr_f(fp);
        X[a] = v.w;  Y[a] = v.z;
        hA[4] = v.x; hD3[4] = v.y;
    }
    __syncthreads();                            // b1

    // ---- Level 1: lo=X(cD_1), hi=Y(cD_2), D=4 -> r1 into Z over granules [4,266) ----
    {
        float r[4];
        level_acc<4, 8>(X, Y, 4 + t, r);
        *(float4*)(Z + paddr_g(4 + t)) = make_float4(r[0], r[1], r[2], r[3]);
        if (t < 6) {
            float rt[4];
            level_acc<4, 8>(X, Y, 260 + t, rt);
            *(float4*)(Z + paddr_g(260 + t)) = make_float4(rt[0], rt[1], rt[2], rt[3]);
        }
    }
    __syncthreads();                            // b2: all X/Y reads complete

    // ---- overwrite: X = cD_3, Y = cA (from held registers) ----
#pragma unroll
    for (int j = 0; j < 4; ++j) {
        const int a = paddr_f(t + (j << 8));
        X[a] = hD3[j];  Y[a] = hA[j];
    }
    if (t < 52) {
        const int a = paddr_f(1024 + t);
        X[a] = hD3[4];  Y[a] = hA[4];
    }
    __syncthreads();                            // b3

    // ---- Level 2: lo=Z(r1), hi=X(cD_3), D=2 -> r2 in regs over granules [6,264) ----
    float r2[4], r2t[4];
    level_acc<2, 5>(Z, X, 6 + t, r2);
    if (t < 2) level_acc<2, 5>(Z, X, 262 + t, r2t);
    __syncthreads();                            // b4: all Z/X reads complete

    *(float4*)(X + paddr_g(6 + t)) = make_float4(r2[0], r2[1], r2[2], r2[3]);
    if (t < 2) *(float4*)(X + paddr_g(262 + t)) = make_float4(r2t[0], r2t[1], r2t[2], r2t[3]);
    __syncthreads();                            // b5

    // ---- Level 3: lo=X(r2), hi=Y(cA), D=1, granules [7,263) -> global ----
    float r3[4];
    level_acc<1, 3>(X, Y, 7 + t, r3);
    *(float4*)(out + (size_t)row * T + t0 + (t << 2)) =
        make_float4(r3[0], r3[1], r3[2], r3[3]);
}

extern "C" void kernel_launch(void* const* d_in, const int* in_sizes, int n_in,
                              void* d_out, int out_size, void* d_ws, size_t ws_size,
                              hipStream_t stream)
{
    const float* coeffs = (const float*)d_in[0];
    float* out = (float*)d_out;
    const int nrows = in_sizes[0] / (T * 4);    // 4096
    iswt_kernel<<<nrows * 4, 256, 0, stream>>>(coeffs, out);
}